// Round 5
// baseline (1777.527 us; speedup 1.0000x reference)
//
#include <hip/hip_runtime.h>
#include <hip/hip_cooperative_groups.h>
#include <hip/hip_bf16.h>
#include <math.h>

namespace cg = cooperative_groups;

#define NGRAPHS 256
#define BSHIFT 8
#define NBUCK 512    // 256-node buckets; covers N up to 131072
#define NSORT 256    // chunks for bhist/bscatter
#define GCHUNK 1024
#define SMASK 0x00FFFFFFu  // low 24 bits = src (N < 2^24)

__device__ __forceinline__ float bf2f(unsigned short u) {
    return __uint_as_float((unsigned)u << 16);
}
__device__ __forceinline__ unsigned short f2bf(float f) {
    unsigned u = __float_as_uint(f);
    unsigned r = (u + 0x7FFFu + ((u >> 16) & 1u)) >> 16;  // RNE
    return (unsigned short)r;
}

struct SMLin { float rel[2048]; float root[2048]; float b[64]; float part[512]; };
struct SMSort { int h[256]; int s[256]; int c[256]; };
struct SMBn { float sc[64]; float sh[64]; };
union SM {
    int hist[NBUCK];
    int sbuf[GCHUNK];
    int scan[512];
    SMSort sort;
    SMLin lin;
    SMBn bn;
};

struct MegaP {
    const float* x; const int* src; const int* dst; const int* batch;
    int N, E; float invN;
    const float *w_rel1, *w_root1, *b1, *g1, *be1;
    const float *w_rel2, *w_root2, *b2, *g2, *be2;
    const float *w_rel3, *w_root3, *b3, *g3, *be3;
    const float *w_rel4, *w_root4, *b4, *g4, *be4;
    const float *w_lin1, *b_lin1, *w_lin2, *b_lin2;
    int* hmat; int* bstart; unsigned* ebuf; int* csr; int* row_start;
    float* agg; unsigned short* y1b; unsigned short* hb; float* bufA;
    float* gs;            // 4 layers x 128 floats (sum | sumsq), device-atomic accumulated
    float* pooled; float* cntg;
    float* out;
};

// ---------------- phase A: bhist (blocks < NSORT) | zero + layer-1 rel matmul (blocks >= NSORT) ----------------
__device__ void phA(const MegaP& p, SM* sm) {
    int bid = blockIdx.x, tid = threadIdx.x;
    if (bid < NSORT) {
        for (int i = tid; i < NBUCK; i += 256) sm->hist[i] = 0;
        __syncthreads();
        int chunk = (p.E + NSORT - 1) / NSORT;
        int lo = bid * chunk;
        int hi = lo + chunk; if (hi > p.E) hi = p.E;
        for (int i = lo + tid; i < hi; i += 256)
            atomicAdd(&sm->hist[__builtin_nontemporal_load(p.dst + i) >> BSHIFT], 1);
        __syncthreads();
        for (int i = tid; i < NBUCK; i += 256)
            p.hmat[(size_t)bid * NBUCK + i] = sm->hist[i];
    } else {
        if (bid == NSORT) {  // zero pooled/cntg + gs accumulators
            for (int i = tid; i < NGRAPHS * 64 + NGRAPHS; i += 256) p.pooled[i] = 0.f;
            for (int i = tid; i < 512; i += 256) p.gs[i] = 0.f;
        }
        // lin_rel: y1b = x @ w_rel1  (64 -> 16, bf16 out)
        float* s_rel = sm->lin.rel;
        for (int i = tid; i < 64 * 16; i += 256) s_rel[i] = p.w_rel1[i];
        __syncthreads();
        int total = p.N * 4;
        int nb = gridDim.x - NSORT;
        for (int i = (bid - NSORT) * 256 + tid; i < total; i += nb * 256) {
            int n = i >> 2, c0 = (i & 3) << 2;
            const float4* mp = (const float4*)(p.x + (size_t)n * 64);
            float4 acc; acc.x = 0.f; acc.y = 0.f; acc.z = 0.f; acc.w = 0.f;
#pragma unroll
            for (int k2 = 0; k2 < 16; k2++) {
                float4 v = mp[k2];
                const float* wr = &s_rel[(k2 * 4) * 16 + c0];
                float4 w0 = *(const float4*)(wr);
                float4 w1 = *(const float4*)(wr + 16);
                float4 w2 = *(const float4*)(wr + 32);
                float4 w3 = *(const float4*)(wr + 48);
                acc.x += v.x * w0.x + v.y * w1.x + v.z * w2.x + v.w * w3.x;
                acc.y += v.x * w0.y + v.y * w1.y + v.z * w2.y + v.w * w3.y;
                acc.z += v.x * w0.z + v.y * w1.z + v.z * w2.z + v.w * w3.z;
                acc.w += v.x * w0.w + v.y * w1.w + v.z * w2.w + v.w * w3.w;
            }
            ushort4 o; o.x = f2bf(acc.x); o.y = f2bf(acc.y); o.z = f2bf(acc.z); o.w = f2bf(acc.w);
            *(ushort4*)(p.y1b + (size_t)n * 16 + c0) = o;
        }
    }
}

// ---------------- phase B: column scan + bucket scan (block 0 only; 256 threads, 512 cols) ----------------
__device__ void phB(const MegaP& p, SM* sm) {
    int t = threadIdx.x;
    int run0 = 0, run1 = 0;
    for (int r = 0; r < NSORT; r++) {
        size_t base = (size_t)r * NBUCK;
        int v0 = p.hmat[base + t];
        int v1 = p.hmat[base + 256 + t];
        p.hmat[base + t] = run0;
        p.hmat[base + 256 + t] = run1;
        run0 += v0; run1 += v1;
    }
    sm->scan[t] = run0; sm->scan[256 + t] = run1;
    __syncthreads();
    for (int off = 1; off < 256; off <<= 1) {
        int v0 = (t >= off) ? sm->scan[t - off] : 0;
        int v1 = (t >= off) ? sm->scan[256 + t - off] : 0;
        __syncthreads();
        sm->scan[t] += v0; sm->scan[256 + t] += v1;
        __syncthreads();
    }
    int lowtot = sm->scan[255];
    int incU = sm->scan[256 + t] + lowtot;
    p.bstart[t] = sm->scan[t] - run0;
    p.bstart[256 + t] = incU - run1;
    if (t == 255) p.bstart[NBUCK] = incU;
}

// ---------------- phase C: scatter into bucket-ordered ebuf (grid-stride chunks) ----------------
__device__ void phC(const MegaP& p, SM* sm) {
    int tid = threadIdx.x;
    for (int b = blockIdx.x; b < NSORT; b += gridDim.x) {
        for (int i = tid; i < NBUCK; i += 256)
            sm->hist[i] = p.bstart[i] + p.hmat[(size_t)b * NBUCK + i];
        __syncthreads();
        int chunk = (p.E + NSORT - 1) / NSORT;
        int lo = b * chunk;
        int hi = lo + chunk; if (hi > p.E) hi = p.E;
        for (int i = lo + tid; i < hi; i += 256) {
            int d = __builtin_nontemporal_load(p.dst + i);
            int s = __builtin_nontemporal_load(p.src + i);
            int pos = atomicAdd(&sm->hist[d >> BSHIFT], 1);
            p.ebuf[pos] = (unsigned)s | ((unsigned)(d & 255) << 24);
        }
        __syncthreads();
    }
}

// ---------------- phase D: per-bucket LDS counting sort -> CSR + row_start (grid-stride buckets) ----------------
__device__ void phD(const MegaP& p, SM* sm) {
    int tid = threadIdx.x;
    for (int b = blockIdx.x; b < NBUCK; b += gridDim.x) {
        int e0 = p.bstart[b], e1 = p.bstart[b + 1];
        sm->sort.h[tid] = 0;
        __syncthreads();
        for (int i = e0 + tid; i < e1; i += 256)
            atomicAdd(&sm->sort.h[__builtin_nontemporal_load(p.ebuf + i) >> 24], 1);
        __syncthreads();
        sm->sort.s[tid] = sm->sort.h[tid];
        __syncthreads();
        for (int off = 1; off < 256; off <<= 1) {
            int v = (tid >= off) ? sm->sort.s[tid - off] : 0;
            __syncthreads();
            sm->sort.s[tid] += v;
            __syncthreads();
        }
        {
            int inc = sm->sort.s[tid];
            int ex = inc - sm->sort.h[tid];
            sm->sort.c[tid] = e0 + ex;
            int node = (b << BSHIFT) + tid;
            if (node < p.N) p.row_start[node] = e0 + ex;
            if (node == p.N - 1) p.row_start[p.N] = e0 + inc;
        }
        __syncthreads();
        for (int i = e0 + tid; i < e1; i += 256) {
            unsigned w = __builtin_nontemporal_load(p.ebuf + i);
            int pos = atomicAdd(&sm->sort.c[w >> 24], 1);
            p.csr[pos] = (int)(w & SMASK);
        }
        __syncthreads();
    }
}

// ---------------- gather: LDS-staged csr + exact-bounds batches (round-3 proven), grid-stride groups ----------------
template <int C>
__device__ void ph_gather(const MegaP& p, SM* sm, const unsigned short* h) {
    constexpr int LPR = C / 4;
    constexpr int EPP = 64 / LPR;
    constexpr int DEPTH = 32 / EPP;
    int lane = threadIdx.x & 63;
    int w = threadIdx.x >> 6;
    int es = lane / LPR;
    int cq = (lane % LPR) * 4;
    int ngrp = (p.N + 3) >> 2;
    for (int grp = blockIdx.x; grp < ngrp; grp += gridDim.x) {
        int nb = grp * 4;
        int wid = nb + w;
        bool act = wid < p.N;
        int nb_end = nb + 4; if (nb_end > p.N) nb_end = p.N;
        int eb0 = p.row_start[nb];
        int eb1 = p.row_start[nb_end];
        int r0 = act ? p.row_start[wid] : 0;
        int r1 = act ? p.row_start[wid + 1] : 0;
        float a0 = 0.f, a1 = 0.f, a2 = 0.f, a3 = 0.f;
        for (int base = eb0; base < eb1; base += GCHUNK) {
            int len = eb1 - base; if (len > GCHUNK) len = GCHUNK;
            __syncthreads();
            for (int i = threadIdx.x; i < len; i += 256)
                sm->sbuf[i] = __builtin_nontemporal_load(p.csr + base + i);
            __syncthreads();
            if (act) {
                int lo = (r0 > base ? r0 : base) - base;
                int hiv = r1 < base + len ? r1 : base + len;
                int hi = hiv - base;
                if (hi > lo) {
                    int nfull = (hi - lo) >> 5;
                    int j0 = lo;
                    for (int bb = 0; bb < nfull; bb++, j0 += 32) {
                        int s[DEPTH];
#pragma unroll
                        for (int u = 0; u < DEPTH; u++) s[u] = sm->sbuf[j0 + u * EPP + es];
                        ushort4 v[DEPTH];
#pragma unroll
                        for (int u = 0; u < DEPTH; u++)
                            v[u] = *(const ushort4*)(h + (size_t)s[u] * C + cq);
#pragma unroll
                        for (int u = 0; u < DEPTH; u++) {
                            a0 += bf2f(v[u].x); a1 += bf2f(v[u].y);
                            a2 += bf2f(v[u].z); a3 += bf2f(v[u].w);
                        }
                    }
                    for (int j = j0 + es; j < hi; j += EPP) {
                        int s = sm->sbuf[j];
                        ushort4 v = *(const ushort4*)(h + (size_t)s * C + cq);
                        a0 += bf2f(v.x); a1 += bf2f(v.y); a2 += bf2f(v.z); a3 += bf2f(v.w);
                    }
                }
            }
        }
#pragma unroll
        for (int off = LPR; off < 64; off <<= 1) {
            a0 += __shfl_xor(a0, off, 64);
            a1 += __shfl_xor(a1, off, 64);
            a2 += __shfl_xor(a2, off, 64);
            a3 += __shfl_xor(a3, off, 64);
        }
        if (act && lane < LPR) {
            int deg = r1 - r0;
            float rec = 1.0f / (float)(deg > 0 ? deg : 1);
            float4 o; o.x = a0 * rec; o.y = a1 * rec; o.z = a2 * rec; o.w = a3 * rec;
            *(float4*)(p.agg + (size_t)wid * C + cq) = o;
        }
    }
}

// ---------------- dense layer + BN-stats partials -> device atomicAdd into gs (no fences, no last-block) ----------------
template <int CI, int CO, bool HAS_REL, bool ADD_AGG, bool IN_BF16>
__device__ void ph_lin_stats(const MegaP& p, SM* sm, const void* hroot_v, const float* hrel,
                             const float* w_rel, const float* w_root, const float* bias,
                             float* out, float* gsl) {
    constexpr int QPR = CO / 4;
    int tid = threadIdx.x;
    if (HAS_REL)
        for (int i = tid; i < CI * CO; i += 256) sm->lin.rel[i] = w_rel[i];
    for (int i = tid; i < CI * CO; i += 256) sm->lin.root[i] = w_root[i];
    if (tid < CO) sm->lin.b[tid] = bias[tid];
    __syncthreads();
    int total = p.N * QPR;
    int stride = gridDim.x * 256;  // multiple of QPR -> c0 constant per thread
    float s0 = 0, s1 = 0, s2 = 0, s3 = 0, q0 = 0, q1 = 0, q2 = 0, q3 = 0;
    for (int i = blockIdx.x * 256 + tid; i < total; i += stride) {
        int n = i / QPR, c0 = (i % QPR) * 4;
        float4 acc = *(const float4*)&sm->lin.b[c0];
        if (ADD_AGG) {
            float4 v = ((const float4*)p.agg)[i];
            acc.x += v.x; acc.y += v.y; acc.z += v.z; acc.w += v.w;
        }
#pragma unroll
        for (int cb = 0; cb < CI / 4; cb++) {
            float f0, f1, f2, f3;
            if (IN_BF16) {
                ushort4 v = *(const ushort4*)((const unsigned short*)hroot_v + (size_t)n * CI + cb * 4);
                f0 = bf2f(v.x); f1 = bf2f(v.y); f2 = bf2f(v.z); f3 = bf2f(v.w);
            } else {
                float4 v = *(const float4*)((const float*)hroot_v + (size_t)n * CI + cb * 4);
                f0 = v.x; f1 = v.y; f2 = v.z; f3 = v.w;
            }
            const float* wr = &sm->lin.root[(cb * 4) * CO + c0];
            float4 w0 = *(const float4*)(wr);
            float4 w1 = *(const float4*)(wr + CO);
            float4 w2 = *(const float4*)(wr + 2 * CO);
            float4 w3 = *(const float4*)(wr + 3 * CO);
            acc.x += f0 * w0.x + f1 * w1.x + f2 * w2.x + f3 * w3.x;
            acc.y += f0 * w0.y + f1 * w1.y + f2 * w2.y + f3 * w3.y;
            acc.z += f0 * w0.z + f1 * w1.z + f2 * w2.z + f3 * w3.z;
            acc.w += f0 * w0.w + f1 * w1.w + f2 * w2.w + f3 * w3.w;
            if (HAS_REL) {
                float4 a = *(const float4*)(hrel + (size_t)n * CI + cb * 4);
                const float* we = &sm->lin.rel[(cb * 4) * CO + c0];
                float4 e0 = *(const float4*)(we);
                float4 e1 = *(const float4*)(we + CO);
                float4 e2 = *(const float4*)(we + 2 * CO);
                float4 e3 = *(const float4*)(we + 3 * CO);
                acc.x += a.x * e0.x + a.y * e1.x + a.z * e2.x + a.w * e3.x;
                acc.y += a.x * e0.y + a.y * e1.y + a.z * e2.y + a.w * e3.y;
                acc.z += a.x * e0.z + a.y * e1.z + a.z * e2.z + a.w * e3.z;
                acc.w += a.x * e0.w + a.y * e1.w + a.z * e2.w + a.w * e3.w;
            }
        }
        ((float4*)out)[i] = acc;
        s0 += acc.x; q0 += acc.x * acc.x;
        s1 += acc.y; q1 += acc.y * acc.y;
        s2 += acc.z; q2 += acc.z * acc.z;
        s3 += acc.w; q3 += acc.w * acc.w;
    }
#pragma unroll
    for (int off = QPR; off < 64; off <<= 1) {
        s0 += __shfl_xor(s0, off, 64); q0 += __shfl_xor(q0, off, 64);
        s1 += __shfl_xor(s1, off, 64); q1 += __shfl_xor(q1, off, 64);
        s2 += __shfl_xor(s2, off, 64); q2 += __shfl_xor(q2, off, 64);
        s3 += __shfl_xor(s3, off, 64); q3 += __shfl_xor(q3, off, 64);
    }
    int lane = tid & 63;
    int w = tid >> 6;
    if (lane < QPR) {
        int cq = lane * 4;
        float* pr = &sm->lin.part[w * 2 * CO];
        pr[cq + 0] = s0; pr[CO + cq + 0] = q0;
        pr[cq + 1] = s1; pr[CO + cq + 1] = q1;
        pr[cq + 2] = s2; pr[CO + cq + 2] = q2;
        pr[cq + 3] = s3; pr[CO + cq + 3] = q3;
    }
    __syncthreads();
    if (tid < 2 * CO) {
        float v = sm->lin.part[tid] + sm->lin.part[2 * CO + tid] +
                  sm->lin.part[4 * CO + tid] + sm->lin.part[6 * CO + tid];
        atomicAdd(&gsl[tid], v);
    }
}

// ---------------- BN apply + ELU (scale/shift recomputed per block from gs: no extra sync needed) ----------------
template <int CO>
__device__ void ph_bn_elu(const MegaP& p, SM* sm, const float* gsl, const float* g, const float* be) {
    int tid = threadIdx.x;
    if (tid < CO) {
        float mean = gsl[tid] * p.invN;
        float var = gsl[CO + tid] * p.invN - mean * mean;
        float sc = g[tid] * rsqrtf(var + 1e-5f);
        sm->bn.sc[tid] = sc;
        sm->bn.sh[tid] = be[tid] - mean * sc;
    }
    __syncthreads();
    int total = p.N * (CO / 4);
    int stride = gridDim.x * 256;
    for (int i = blockIdx.x * 256 + tid; i < total; i += stride) {
        float4 v = ((const float4*)p.bufA)[i];
        int cq = (i % (CO / 4)) * 4;
        v.x = v.x * sm->bn.sc[cq + 0] + sm->bn.sh[cq + 0];
        v.y = v.y * sm->bn.sc[cq + 1] + sm->bn.sh[cq + 1];
        v.z = v.z * sm->bn.sc[cq + 2] + sm->bn.sh[cq + 2];
        v.w = v.w * sm->bn.sc[cq + 3] + sm->bn.sh[cq + 3];
        v.x = v.x > 0.f ? v.x : expm1f(v.x);
        v.y = v.y > 0.f ? v.y : expm1f(v.y);
        v.z = v.z > 0.f ? v.z : expm1f(v.z);
        v.w = v.w > 0.f ? v.w : expm1f(v.w);
        ushort4 o;
        o.x = f2bf(v.x); o.y = f2bf(v.y); o.z = f2bf(v.z); o.w = f2bf(v.w);
        ((ushort4*)p.hb)[i] = o;
    }
}

// ---------------- layer 4: BN + ELU + pool (run-length segmented, 16 nodes/wave, grid-stride) ----------------
__device__ void ph_pool(const MegaP& p, SM* sm, const float* gsl) {
    int tid = threadIdx.x;
    if (tid < 64) {
        float mean = gsl[tid] * p.invN;
        float var = gsl[64 + tid] * p.invN - mean * mean;
        float sc = p.g4[tid] * rsqrtf(var + 1e-5f);
        sm->bn.sc[tid] = sc;
        sm->bn.sh[tid] = p.be4[tid] - mean * sc;
    }
    __syncthreads();
    int lane = tid & 63;
    int w = tid >> 6;
    float scl = sm->bn.sc[lane];
    float shl = sm->bn.sh[lane];
    int ngrp = (p.N + 15) / 16;
    for (int gi = blockIdx.x * 4 + w; gi < ngrp; gi += gridDim.x * 4) {
        int n0 = gi * 16;
        int nmax = p.N - n0; if (nmax > 16) nmax = 16;
        int cur = p.batch[n0];
        float acc = 0.f, run = 0.f;
        for (int k = 0; k < nmax; k++) {
            int gg = p.batch[n0 + k];
            if (gg != cur) {
                atomicAdd(&p.pooled[(size_t)cur * 64 + lane], acc);
                if (lane == 0) atomicAdd(&p.cntg[cur], run);
                cur = gg; acc = 0.f; run = 0.f;
            }
            float v = p.bufA[(size_t)(n0 + k) * 64 + lane] * scl + shl;
            v = v > 0.f ? v : expm1f(v);
            acc += v;
            run += 1.f;
        }
        atomicAdd(&p.pooled[(size_t)cur * 64 + lane], acc);
        if (lane == 0) atomicAdd(&p.cntg[cur], run);
    }
}

// ---------------- head (block 0; 256 threads == 256 graphs) ----------------
__device__ void ph_head(const MegaP& p) {
    int g = threadIdx.x;
    float rec = 1.0f / fmaxf(p.cntg[g], 1.0f);
    float pv[64];
    {
        const float4* pp = (const float4*)(p.pooled + (size_t)g * 64);
#pragma unroll
        for (int i = 0; i < 16; i++) {
            float4 v = pp[i];
            pv[4 * i + 0] = v.x * rec; pv[4 * i + 1] = v.y * rec;
            pv[4 * i + 2] = v.z * rec; pv[4 * i + 3] = v.w * rec;
        }
    }
    float lg[10];
#pragma unroll
    for (int t = 0; t < 10; t++) lg[t] = p.b_lin2[t];
#pragma unroll 1
    for (int j = 0; j < 64; j++) {
        float a = p.b_lin1[j];
#pragma unroll
        for (int k = 0; k < 64; k++) a += pv[k] * p.w_lin1[k * 64 + j];
        a = fmaxf(a, 0.f);
#pragma unroll
        for (int t = 0; t < 10; t++) lg[t] += a * p.w_lin2[j * 10 + t];
    }
    float m = -1e30f;
#pragma unroll
    for (int t = 0; t < 10; t++) m = fmaxf(m, lg[t]);
    float s = 0.f;
#pragma unroll
    for (int t = 0; t < 10; t++) s += expf(lg[t] - m);
    float lse = m + logf(s);
#pragma unroll
    for (int t = 0; t < 10; t++) p.out[(size_t)g * 10 + t] = lg[t] - lse;
}

// ---------------- the cooperative megakernel: 16 grid syncs replace 16 kernel boundaries ----------------
__global__ __launch_bounds__(256, 4) void k_mega(MegaP p) {
    __shared__ SM sm;
    cg::grid_group grid = cg::this_grid();

    phA(p, &sm);                                    grid.sync();
    if (blockIdx.x == 0) phB(p, &sm);               grid.sync();
    phC(p, &sm);                                    grid.sync();
    phD(p, &sm);                                    grid.sync();

    // L1: 64 -> 16
    ph_gather<16>(p, &sm, p.y1b);                   grid.sync();
    ph_lin_stats<64, 16, false, true, false>(p, &sm, p.x, nullptr, nullptr, p.w_root1, p.b1, p.bufA, p.gs + 0);
                                                    grid.sync();
    ph_bn_elu<16>(p, &sm, p.gs + 0, p.g1, p.be1);   grid.sync();
    // L2: 16 -> 32
    ph_gather<16>(p, &sm, p.hb);                    grid.sync();
    ph_lin_stats<16, 32, true, false, true>(p, &sm, p.hb, p.agg, p.w_rel2, p.w_root2, p.b2, p.bufA, p.gs + 128);
                                                    grid.sync();
    ph_bn_elu<32>(p, &sm, p.gs + 128, p.g2, p.be2); grid.sync();
    // L3: 32 -> 32
    ph_gather<32>(p, &sm, p.hb);                    grid.sync();
    ph_lin_stats<32, 32, true, false, true>(p, &sm, p.hb, p.agg, p.w_rel3, p.w_root3, p.b3, p.bufA, p.gs + 256);
                                                    grid.sync();
    ph_bn_elu<32>(p, &sm, p.gs + 256, p.g3, p.be3); grid.sync();
    // L4: 32 -> 64
    ph_gather<32>(p, &sm, p.hb);                    grid.sync();
    ph_lin_stats<32, 64, true, false, true>(p, &sm, p.hb, p.agg, p.w_rel4, p.w_root4, p.b4, p.bufA, p.gs + 384);
                                                    grid.sync();
    ph_pool(p, &sm, p.gs + 384);                    grid.sync();
    if (blockIdx.x == 0) ph_head(p);
}

// ---------------- fallback wrappers (ordinary launches; used only if cooperative launch unavailable) ----------------
__global__ __launch_bounds__(256) void w_A(MegaP p) { __shared__ SM sm; phA(p, &sm); }
__global__ __launch_bounds__(256) void w_B(MegaP p) { __shared__ SM sm; if (blockIdx.x == 0) phB(p, &sm); }
__global__ __launch_bounds__(256) void w_C(MegaP p) { __shared__ SM sm; phC(p, &sm); }
__global__ __launch_bounds__(256) void w_D(MegaP p) { __shared__ SM sm; phD(p, &sm); }
__global__ __launch_bounds__(256) void w_G16a(MegaP p) { __shared__ SM sm; ph_gather<16>(p, &sm, p.y1b); }
__global__ __launch_bounds__(256) void w_G16b(MegaP p) { __shared__ SM sm; ph_gather<16>(p, &sm, p.hb); }
__global__ __launch_bounds__(256) void w_G32(MegaP p) { __shared__ SM sm; ph_gather<32>(p, &sm, p.hb); }
__global__ __launch_bounds__(256) void w_L1(MegaP p) { __shared__ SM sm; ph_lin_stats<64, 16, false, true, false>(p, &sm, p.x, nullptr, nullptr, p.w_root1, p.b1, p.bufA, p.gs + 0); }
__global__ __launch_bounds__(256) void w_L2(MegaP p) { __shared__ SM sm; ph_lin_stats<16, 32, true, false, true>(p, &sm, p.hb, p.agg, p.w_rel2, p.w_root2, p.b2, p.bufA, p.gs + 128); }
__global__ __launch_bounds__(256) void w_L3(MegaP p) { __shared__ SM sm; ph_lin_stats<32, 32, true, false, true>(p, &sm, p.hb, p.agg, p.w_rel3, p.w_root3, p.b3, p.bufA, p.gs + 256); }
__global__ __launch_bounds__(256) void w_L4(MegaP p) { __shared__ SM sm; ph_lin_stats<32, 64, true, false, true>(p, &sm, p.hb, p.agg, p.w_rel4, p.w_root4, p.b4, p.bufA, p.gs + 384); }
__global__ __launch_bounds__(256) void w_B1(MegaP p) { __shared__ SM sm; ph_bn_elu<16>(p, &sm, p.gs + 0, p.g1, p.be1); }
__global__ __launch_bounds__(256) void w_B2(MegaP p) { __shared__ SM sm; ph_bn_elu<32>(p, &sm, p.gs + 128, p.g2, p.be2); }
__global__ __launch_bounds__(256) void w_B3(MegaP p) { __shared__ SM sm; ph_bn_elu<32>(p, &sm, p.gs + 256, p.g3, p.be3); }
__global__ __launch_bounds__(256) void w_P(MegaP p) { __shared__ SM sm; ph_pool(p, &sm, p.gs + 384); }
__global__ __launch_bounds__(256) void w_H(MegaP p) { if (blockIdx.x == 0) ph_head(p); }

extern "C" void kernel_launch(void* const* d_in, const int* in_sizes, int n_in,
                              void* d_out, int out_size, void* d_ws, size_t ws_size,
                              hipStream_t stream) {
    const float* x = (const float*)d_in[0];
    const int* ei = (const int*)d_in[1];
    const int* batch = (const int*)d_in[2];
    const int N = in_sizes[0] / 64;
    const int E = in_sizes[1] / 2;

    MegaP P;
    P.x = x; P.src = ei; P.dst = ei + E; P.batch = batch;
    P.N = N; P.E = E; P.invN = 1.0f / (float)N;
    P.w_rel1 = (const float*)d_in[3];  P.w_root1 = (const float*)d_in[4];
    P.b1 = (const float*)d_in[5];      P.g1 = (const float*)d_in[6];   P.be1 = (const float*)d_in[7];
    P.w_rel2 = (const float*)d_in[8];  P.w_root2 = (const float*)d_in[9];
    P.b2 = (const float*)d_in[10];     P.g2 = (const float*)d_in[11];  P.be2 = (const float*)d_in[12];
    P.w_rel3 = (const float*)d_in[13]; P.w_root3 = (const float*)d_in[14];
    P.b3 = (const float*)d_in[15];     P.g3 = (const float*)d_in[16];  P.be3 = (const float*)d_in[17];
    P.w_rel4 = (const float*)d_in[18]; P.w_root4 = (const float*)d_in[19];
    P.b4 = (const float*)d_in[20];     P.g4 = (const float*)d_in[21];  P.be4 = (const float*)d_in[22];
    P.w_lin1 = (const float*)d_in[23]; P.b_lin1 = (const float*)d_in[24];
    P.w_lin2 = (const float*)d_in[25]; P.b_lin2 = (const float*)d_in[26];

    char* ws = (char*)d_ws;
    size_t off = 0;
    auto alloc = [&](size_t bytes) { size_t o = off; off += (bytes + 255) & ~(size_t)255; return o; };
    P.hmat = (int*)(ws + alloc((size_t)NSORT * NBUCK * 4));
    P.bstart = (int*)(ws + alloc((size_t)(NBUCK + 1) * 4));
    P.ebuf = (unsigned*)(ws + alloc((size_t)E * 4));
    P.csr = (int*)(ws + alloc((size_t)E * 4));
    P.row_start = (int*)(ws + alloc((size_t)(N + 1) * 4));
    P.agg = (float*)(ws + alloc((size_t)N * 32 * 4));
    P.y1b = (unsigned short*)(ws + alloc((size_t)N * 16 * 2));
    P.hb = (unsigned short*)(ws + alloc((size_t)N * 64 * 2));
    P.bufA = (float*)(ws + alloc((size_t)N * 64 * 4));
    P.gs = (float*)(ws + alloc(512 * 4));
    P.pooled = (float*)(ws + alloc((size_t)(NGRAPHS * 64 + NGRAPHS) * 4));
    P.cntg = P.pooled + NGRAPHS * 64;
    P.out = (float*)d_out;

    // one-time capability probe (host-side queries only; capture-safe)
    static int s_grid = -2;
    if (s_grid == -2) {
        int dev = 0; hipGetDevice(&dev);
        int coop = 0; hipDeviceGetAttribute(&coop, hipDeviceAttributeCooperativeLaunch, dev);
        int cus = 0; hipDeviceGetAttribute(&cus, hipDeviceAttributeMultiprocessorCount, dev);
        int nb = 0;
        hipOccupancyMaxActiveBlocksPerMultiprocessor(&nb, (const void*)k_mega, 256, 0);
        s_grid = (coop && nb > 0 && cus > 0) ? nb * cus : 0;
        if (s_grid > 2048) s_grid = 2048;
        if (s_grid < 512) s_grid = 0;  // phase A's block split needs >= 512 blocks
    }

    if (s_grid > 0) {
        void* args[] = {(void*)&P};
        hipError_t e = hipLaunchCooperativeKernel((void*)k_mega, dim3(s_grid), dim3(256), args, 0, stream);
        if (e == hipSuccess) return;
        s_grid = 0;  // permanent fallback
    }

    // fallback: same phases as ordinary launches
    w_A<<<1024, 256, 0, stream>>>(P);
    w_B<<<1, 256, 0, stream>>>(P);
    w_C<<<NSORT, 256, 0, stream>>>(P);
    w_D<<<NBUCK, 256, 0, stream>>>(P);
    w_G16a<<<2048, 256, 0, stream>>>(P);
    w_L1<<<512, 256, 0, stream>>>(P);
    w_B1<<<512, 256, 0, stream>>>(P);
    w_G16b<<<2048, 256, 0, stream>>>(P);
    w_L2<<<512, 256, 0, stream>>>(P);
    w_B2<<<512, 256, 0, stream>>>(P);
    w_G32<<<2048, 256, 0, stream>>>(P);
    w_L3<<<512, 256, 0, stream>>>(P);
    w_B3<<<512, 256, 0, stream>>>(P);
    w_G32<<<2048, 256, 0, stream>>>(P);
    w_L4<<<512, 256, 0, stream>>>(P);
    w_P<<<1024, 256, 0, stream>>>(P);
    w_H<<<1, 256, 0, stream>>>(P);
}

// Round 6
// 604.504 us; speedup vs baseline: 2.9405x; 2.9405x over previous
//
#include <hip/hip_runtime.h>
#include <hip/hip_bf16.h>
#include <math.h>

#define NGRAPHS 256
#define BSHIFT 8
#define NBUCK 512    // 256-node buckets; covers N up to 131072
#define NSORT 256    // chunks for bhist/bscatter
#define LSTAT 1024   // lin_stats blocks (4/CU)
#define GCHUNK 1024
#define SMASK 0x00FFFFFFu  // low 24 bits = src (N < 2^24)

__device__ __forceinline__ float bf2f(unsigned short u) {
    return __uint_as_float((unsigned)u << 16);
}
__device__ __forceinline__ unsigned short f2bf(float f) {
    unsigned u = __float_as_uint(f);
    unsigned r = (u + 0x7FFFu + ((u >> 16) & 1u)) >> 16;  // RNE
    return (unsigned short)r;
}

// ---------------- dispatch 1: bucket histogram (blocks 0..255) || zero gs/pooled + L1 rel matmul (blocks 256+) ----
// The two halves are data-independent; later kernels that consume y1b/gs/pooled are ordered by dispatch boundary.
__global__ __launch_bounds__(256) void k_bhist(const int* __restrict__ dst, int* __restrict__ hmat, int E,
                                               const float* __restrict__ x, const float* __restrict__ w_rel1,
                                               unsigned short* __restrict__ y1b,
                                               float* __restrict__ zbase, int zwords, int N) {
    int bid = blockIdx.x, tid = threadIdx.x;
    if (bid < NSORT) {
        __shared__ int hist[NBUCK];
        for (int i = tid; i < NBUCK; i += 256) hist[i] = 0;
        __syncthreads();
        int chunk = (E + NSORT - 1) / NSORT;
        int lo = bid * chunk;
        int hi = lo + chunk; if (hi > E) hi = E;
        for (int i = lo + tid; i < hi; i += 256)
            atomicAdd(&hist[__builtin_nontemporal_load(dst + i) >> BSHIFT], 1);
        __syncthreads();
        for (int i = tid; i < NBUCK; i += 256)
            hmat[(size_t)bid * NBUCK + i] = hist[i];  // coalesced dump
    } else {
        if (bid == NSORT) {  // zero pooled/cntg + gs accumulators (re-zeroed every launch/replay)
            for (int i = tid; i < zwords; i += 256) zbase[i] = 0.f;
        }
        __shared__ float s_rel[64 * 16];
        for (int i = tid; i < 64 * 16; i += 256) s_rel[i] = w_rel1[i];
        __syncthreads();
        int total = N * 4;
        int nb = gridDim.x - NSORT;
        for (int i = (bid - NSORT) * 256 + tid; i < total; i += nb * 256) {
            int n = i >> 2, c0 = (i & 3) << 2;
            const float4* mp = (const float4*)(x + (size_t)n * 64);
            float4 acc; acc.x = 0.f; acc.y = 0.f; acc.z = 0.f; acc.w = 0.f;
#pragma unroll
            for (int k2 = 0; k2 < 16; k2++) {
                float4 v = mp[k2];
                const float* wr = &s_rel[(k2 * 4) * 16 + c0];
                float4 w0 = *(const float4*)(wr);
                float4 w1 = *(const float4*)(wr + 16);
                float4 w2 = *(const float4*)(wr + 32);
                float4 w3 = *(const float4*)(wr + 48);
                acc.x += v.x * w0.x + v.y * w1.x + v.z * w2.x + v.w * w3.x;
                acc.y += v.x * w0.y + v.y * w1.y + v.z * w2.y + v.w * w3.y;
                acc.z += v.x * w0.z + v.y * w1.z + v.z * w2.z + v.w * w3.z;
                acc.w += v.x * w0.w + v.y * w1.w + v.z * w2.w + v.w * w3.w;
            }
            ushort4 o; o.x = f2bf(acc.x); o.y = f2bf(acc.y); o.z = f2bf(acc.z); o.w = f2bf(acc.w);
            *(ushort4*)(y1b + (size_t)n * 16 + c0) = o;
        }
    }
}

// ---------------- dispatch 2: merged column scan + bucket scan (one block, 512 threads) ----------------
__global__ __launch_bounds__(512) void k_scan(int* __restrict__ hmat, int* __restrict__ bstart) {
    __shared__ int s[512];
    int col = threadIdx.x;
    int run = 0;
#pragma unroll 4
    for (int r = 0; r < NSORT; r++) {
        int v = hmat[(size_t)r * NBUCK + col];
        hmat[(size_t)r * NBUCK + col] = run;
        run += v;
    }
    s[col] = run;
    __syncthreads();
    for (int off = 1; off < 512; off <<= 1) {
        int t = (col >= off) ? s[col - off] : 0;
        __syncthreads();
        s[col] += t;
        __syncthreads();
    }
    bstart[col] = s[col] - run;  // exclusive
    if (col == 511) bstart[NBUCK] = s[511];
}

// ---------------- dispatch 3: scatter into bucket-ordered ebuf ----------------
__global__ __launch_bounds__(256) void k_bscatter(const int* __restrict__ src, const int* __restrict__ dst,
                                                  const int* __restrict__ hmat, const int* __restrict__ bstart,
                                                  unsigned* __restrict__ ebuf, int E) {
    __shared__ int cur[NBUCK];
    for (int i = threadIdx.x; i < NBUCK; i += 256)
        cur[i] = bstart[i] + hmat[(size_t)blockIdx.x * NBUCK + i];
    __syncthreads();
    int chunk = (E + NSORT - 1) / NSORT;
    int lo = blockIdx.x * chunk;
    int hi = lo + chunk; if (hi > E) hi = E;
    for (int i = lo + threadIdx.x; i < hi; i += 256) {
        int d = __builtin_nontemporal_load(dst + i);
        int s = __builtin_nontemporal_load(src + i);
        int p = atomicAdd(&cur[d >> BSHIFT], 1);
        ebuf[p] = (unsigned)s | ((unsigned)(d & 255) << 24);
    }
}

// ---------------- dispatch 4: per-bucket LDS counting sort -> full CSR + row_start ----------------
__global__ __launch_bounds__(256) void k_sort2(const unsigned* __restrict__ ebuf, const int* __restrict__ bstart,
                                               int* __restrict__ csr, int* __restrict__ row_start, int N) {
    __shared__ int hist[256];
    __shared__ int sc[256];
    __shared__ int scur[256];
    int b = blockIdx.x;
    int e0 = bstart[b], e1 = bstart[b + 1];
    hist[threadIdx.x] = 0;
    __syncthreads();
    for (int i = e0 + threadIdx.x; i < e1; i += 256)
        atomicAdd(&hist[__builtin_nontemporal_load(ebuf + i) >> 24], 1);
    __syncthreads();
    sc[threadIdx.x] = hist[threadIdx.x];
    __syncthreads();
    for (int off = 1; off < 256; off <<= 1) {
        int t = (threadIdx.x >= off) ? sc[threadIdx.x - off] : 0;
        __syncthreads();
        sc[threadIdx.x] += t;
        __syncthreads();
    }
    {
        int inc = sc[threadIdx.x];
        int ex = inc - hist[threadIdx.x];
        scur[threadIdx.x] = e0 + ex;
        int node = (b << BSHIFT) + threadIdx.x;
        if (node < N) row_start[node] = e0 + ex;
        if (node == N - 1) row_start[N] = e0 + inc;  // == E
    }
    __syncthreads();
    for (int i = e0 + threadIdx.x; i < e1; i += 256) {
        unsigned w = __builtin_nontemporal_load(ebuf + i);
        int p = atomicAdd(&scur[w >> 24], 1);
        csr[p] = (int)(w & SMASK);
    }
}

// ---------------- gather: LDS-staged csr + fully-predicated clamp batches (4 loads in flight) ----------------
template <int C>
__global__ __launch_bounds__(256) void k_gather(const unsigned short* __restrict__ h,
                                                const int* __restrict__ row_start,
                                                const int* __restrict__ csr, float* __restrict__ agg, int N) {
    constexpr int LPR = C / 4;       // lanes per edge-line
    constexpr int EPP = 64 / LPR;    // edge slots per wave instruction
    constexpr int BATCH = 4 * EPP;   // 4 loads in flight per batch
    __shared__ int sbuf[GCHUNK];
    int lane = threadIdx.x & 63;
    int w = threadIdx.x >> 6;
    int nb = blockIdx.x * 4;
    int wid = nb + w;
    bool act = wid < N;
    int nb_end = nb + 4; if (nb_end > N) nb_end = N;
    int eb0 = row_start[nb];
    int eb1 = row_start[nb_end];
    int r0 = act ? row_start[wid] : 0;
    int r1 = act ? row_start[wid + 1] : 0;
    int es = lane / LPR;
    int cq = (lane % LPR) * 4;

    float a0 = 0.f, a1 = 0.f, a2 = 0.f, a3 = 0.f;
    for (int base = eb0; base < eb1; base += GCHUNK) {
        int len = eb1 - base; if (len > GCHUNK) len = GCHUNK;
        __syncthreads();
        for (int i = threadIdx.x; i < len; i += 256)
            sbuf[i] = __builtin_nontemporal_load(csr + base + i);
        __syncthreads();
        if (act) {
            int lo = (r0 > base ? r0 : base) - base;
            int hiv = r1 < base + len ? r1 : base + len;
            int hi = hiv - base;
            for (int j0 = lo; j0 < hi; j0 += BATCH) {
                int s[4]; bool p[4];
#pragma unroll
                for (int u = 0; u < 4; u++) {
                    int j = j0 + u * EPP + es;
                    p[u] = j < hi;
                    s[u] = sbuf[p[u] ? j : j0];  // clamp to batch base: duplicated hot line, no serial path
                }
                ushort4 v[4];
#pragma unroll
                for (int u = 0; u < 4; u++)
                    v[u] = *(const ushort4*)(h + (size_t)s[u] * C + cq);
#pragma unroll
                for (int u = 0; u < 4; u++) {
                    if (p[u]) {
                        a0 += bf2f(v[u].x); a1 += bf2f(v[u].y);
                        a2 += bf2f(v[u].z); a3 += bf2f(v[u].w);
                    }
                }
            }
        }
    }
#pragma unroll
    for (int off = LPR; off < 64; off <<= 1) {
        a0 += __shfl_xor(a0, off, 64);
        a1 += __shfl_xor(a1, off, 64);
        a2 += __shfl_xor(a2, off, 64);
        a3 += __shfl_xor(a3, off, 64);
    }
    if (act && lane < LPR) {
        int deg = r1 - r0;
        float rec = 1.0f / (float)(deg > 0 ? deg : 1);
        float4 o; o.x = a0 * rec; o.y = a1 * rec; o.z = a2 * rec; o.w = a3 * rec;
        *(float4*)(agg + (size_t)wid * C + cq) = o;
    }
}

// ---------------- dense layer + BN-stat sums -> one atomicAdd per channel into gs (no fence, no finalize) -------
template <int CI, int CO, bool HAS_REL, bool ADD_AGG, bool IN_BF16>
__global__ __launch_bounds__(256) void k_lin_stats(const void* __restrict__ hroot_v, const float* __restrict__ hrel,
                                                   const float* __restrict__ w_rel, const float* __restrict__ w_root,
                                                   const float* __restrict__ bias,
                                                   float* __restrict__ out, float* __restrict__ gsl, int N) {
    constexpr int QPR = CO / 4;
    __shared__ float s_rel[HAS_REL ? CI * CO : 1];
    __shared__ float s_root[CI * CO];
    __shared__ float s_b[CO];
    __shared__ float part[4][2 * CO];
    int tid = threadIdx.x;
    if (HAS_REL)
        for (int i = tid; i < CI * CO; i += 256) s_rel[i] = w_rel[i];
    for (int i = tid; i < CI * CO; i += 256) s_root[i] = w_root[i];
    if (tid < CO) s_b[tid] = bias[tid];
    __syncthreads();

    int total = N * QPR;
    int stride = gridDim.x * 256;  // multiple of QPR -> c0 constant per thread
    float s0 = 0, s1 = 0, s2 = 0, s3 = 0, q0 = 0, q1 = 0, q2 = 0, q3 = 0;
    for (int i = blockIdx.x * 256 + tid; i < total; i += stride) {
        int n = i / QPR, c0 = (i % QPR) * 4;
        float4 acc = *(const float4*)&s_b[c0];
        if (ADD_AGG) {
            float4 v = ((const float4*)hrel)[i];
            acc.x += v.x; acc.y += v.y; acc.z += v.z; acc.w += v.w;
        }
#pragma unroll
        for (int cb = 0; cb < CI / 4; cb++) {
            float f0, f1, f2, f3;
            if (IN_BF16) {
                ushort4 v = *(const ushort4*)((const unsigned short*)hroot_v + (size_t)n * CI + cb * 4);
                f0 = bf2f(v.x); f1 = bf2f(v.y); f2 = bf2f(v.z); f3 = bf2f(v.w);
            } else {
                float4 v = *(const float4*)((const float*)hroot_v + (size_t)n * CI + cb * 4);
                f0 = v.x; f1 = v.y; f2 = v.z; f3 = v.w;
            }
            const float* wr = &s_root[(cb * 4) * CO + c0];
            float4 w0 = *(const float4*)(wr);
            float4 w1 = *(const float4*)(wr + CO);
            float4 w2 = *(const float4*)(wr + 2 * CO);
            float4 w3 = *(const float4*)(wr + 3 * CO);
            acc.x += f0 * w0.x + f1 * w1.x + f2 * w2.x + f3 * w3.x;
            acc.y += f0 * w0.y + f1 * w1.y + f2 * w2.y + f3 * w3.y;
            acc.z += f0 * w0.z + f1 * w1.z + f2 * w2.z + f3 * w3.z;
            acc.w += f0 * w0.w + f1 * w1.w + f2 * w2.w + f3 * w3.w;
            if (HAS_REL) {
                float4 a = *(const float4*)(hrel + (size_t)n * CI + cb * 4);
                const float* we = &s_rel[(cb * 4) * CO + c0];
                float4 e0 = *(const float4*)(we);
                float4 e1 = *(const float4*)(we + CO);
                float4 e2 = *(const float4*)(we + 2 * CO);
                float4 e3 = *(const float4*)(we + 3 * CO);
                acc.x += a.x * e0.x + a.y * e1.x + a.z * e2.x + a.w * e3.x;
                acc.y += a.x * e0.y + a.y * e1.y + a.z * e2.y + a.w * e3.y;
                acc.z += a.x * e0.z + a.y * e1.z + a.z * e2.z + a.w * e3.z;
                acc.w += a.x * e0.w + a.y * e1.w + a.z * e2.w + a.w * e3.w;
            }
        }
        ((float4*)out)[i] = acc;
        s0 += acc.x; q0 += acc.x * acc.x;
        s1 += acc.y; q1 += acc.y * acc.y;
        s2 += acc.z; q2 += acc.z * acc.z;
        s3 += acc.w; q3 += acc.w * acc.w;
    }
#pragma unroll
    for (int off = QPR; off < 64; off <<= 1) {
        s0 += __shfl_xor(s0, off, 64); q0 += __shfl_xor(q0, off, 64);
        s1 += __shfl_xor(s1, off, 64); q1 += __shfl_xor(q1, off, 64);
        s2 += __shfl_xor(s2, off, 64); q2 += __shfl_xor(q2, off, 64);
        s3 += __shfl_xor(s3, off, 64); q3 += __shfl_xor(q3, off, 64);
    }
    int lane = tid & 63;
    int w = tid >> 6;
    if (lane < QPR) {
        int cq = lane * 4;
        part[w][cq + 0] = s0; part[w][CO + cq + 0] = q0;
        part[w][cq + 1] = s1; part[w][CO + cq + 1] = q1;
        part[w][cq + 2] = s2; part[w][CO + cq + 2] = q2;
        part[w][cq + 3] = s3; part[w][CO + cq + 3] = q3;
    }
    __syncthreads();
    if (tid < 2 * CO) {
        float v = part[0][tid] + part[1][tid] + part[2][tid] + part[3][tid];
        atomicAdd(&gsl[tid], v);  // 128 addresses; ordering to consumer = next kernel boundary
    }
}

// ---------------- BN apply + ELU: scale/shift from finished gs sums; write bf16 (layers 1-3) ----------------
template <int CO>
__global__ __launch_bounds__(256) void k_bn_elu(const float* __restrict__ h, const float* __restrict__ gsl,
                                                const float* __restrict__ g, const float* __restrict__ be,
                                                unsigned short* __restrict__ hb, float invN, int N) {
    __shared__ float sc[CO], sh[CO];
    if (threadIdx.x < CO) {
        int c = threadIdx.x;
        float mean = gsl[c] * invN;
        float var = gsl[CO + c] * invN - mean * mean;
        float s = g[c] * rsqrtf(var + 1e-5f);
        sc[c] = s;
        sh[c] = be[c] - mean * s;
    }
    __syncthreads();
    int total = N * (CO / 4);
    int i = blockIdx.x * 256 + threadIdx.x;
    if (i >= total) return;
    float4 v = ((const float4*)h)[i];
    int cq = (i % (CO / 4)) * 4;
    v.x = v.x * sc[cq + 0] + sh[cq + 0];
    v.y = v.y * sc[cq + 1] + sh[cq + 1];
    v.z = v.z * sc[cq + 2] + sh[cq + 2];
    v.w = v.w * sc[cq + 3] + sh[cq + 3];
    v.x = v.x > 0.f ? v.x : expm1f(v.x);
    v.y = v.y > 0.f ? v.y : expm1f(v.y);
    v.z = v.z > 0.f ? v.z : expm1f(v.z);
    v.w = v.w > 0.f ? v.w : expm1f(v.w);
    ushort4 o;
    o.x = f2bf(v.x); o.y = f2bf(v.y); o.z = f2bf(v.z); o.w = f2bf(v.w);
    ((ushort4*)hb)[i] = o;
}

// ---------------- layer 4: BN + ELU + global mean pool fused (16 nodes/wave, fp32, no fences) ----------------
__global__ __launch_bounds__(256) void k_bn_elu_pool(const float* __restrict__ h, const float* __restrict__ gsl,
                                                     const float* __restrict__ g, const float* __restrict__ be,
                                                     const int* __restrict__ batch,
                                                     float* __restrict__ pooled, float* __restrict__ cntg,
                                                     float invN, int N) {
    __shared__ float sc[64], sh[64];
    if (threadIdx.x < 64) {
        int c = threadIdx.x;
        float mean = gsl[c] * invN;
        float var = gsl[64 + c] * invN - mean * mean;
        float s = g[c] * rsqrtf(var + 1e-5f);
        sc[c] = s;
        sh[c] = be[c] - mean * s;
    }
    __syncthreads();
    int lane = threadIdx.x & 63;  // lane == channel
    int wid = blockIdx.x * 4 + (threadIdx.x >> 6);
    int n0 = wid * 16;
    if (n0 >= N) return;
    float scl = sc[lane];
    float shl = sh[lane];
    int nmax = N - n0; if (nmax > 16) nmax = 16;
    int cur = batch[n0];
    float acc = 0.f;
    float run = 0.f;
    for (int k = 0; k < nmax; k++) {
        int gg = batch[n0 + k];
        if (gg != cur) {
            atomicAdd(&pooled[(size_t)cur * 64 + lane], acc);
            if (lane == 0) atomicAdd(&cntg[cur], run);
            cur = gg; acc = 0.f; run = 0.f;
        }
        float v = h[(size_t)(n0 + k) * 64 + lane] * scl + shl;
        v = v > 0.f ? v : expm1f(v);
        acc += v;
        run += 1.f;
    }
    atomicAdd(&pooled[(size_t)cur * 64 + lane], acc);
    if (lane == 0) atomicAdd(&cntg[cur], run);
}

// ---------------- head ----------------
__global__ __launch_bounds__(256) void k_head(const float* __restrict__ pooled, const float* __restrict__ cntg,
                                              const float* __restrict__ w1, const float* __restrict__ b1,
                                              const float* __restrict__ w2, const float* __restrict__ b2,
                                              float* __restrict__ out) {
    int g = threadIdx.x;  // 256 threads == 256 graphs
    float rec = 1.0f / fmaxf(cntg[g], 1.0f);
    float p[64];
    {
        const float4* pp = (const float4*)(pooled + (size_t)g * 64);
#pragma unroll
        for (int i = 0; i < 16; i++) {
            float4 v = pp[i];
            p[4 * i + 0] = v.x * rec; p[4 * i + 1] = v.y * rec;
            p[4 * i + 2] = v.z * rec; p[4 * i + 3] = v.w * rec;
        }
    }
    float lg[10];
#pragma unroll
    for (int t = 0; t < 10; t++) lg[t] = b2[t];
#pragma unroll 1
    for (int j = 0; j < 64; j++) {
        float a = b1[j];
#pragma unroll
        for (int k = 0; k < 64; k++) a += p[k] * w1[k * 64 + j];  // uniform -> s_load
        a = fmaxf(a, 0.f);
#pragma unroll
        for (int t = 0; t < 10; t++) lg[t] += a * w2[j * 10 + t];
    }
    float m = -1e30f;
#pragma unroll
    for (int t = 0; t < 10; t++) m = fmaxf(m, lg[t]);
    float s = 0.f;
#pragma unroll
    for (int t = 0; t < 10; t++) s += expf(lg[t] - m);
    float lse = m + logf(s);
#pragma unroll
    for (int t = 0; t < 10; t++) out[(size_t)g * 10 + t] = lg[t] - lse;
}

extern "C" void kernel_launch(void* const* d_in, const int* in_sizes, int n_in,
                              void* d_out, int out_size, void* d_ws, size_t ws_size,
                              hipStream_t stream) {
    const float* x = (const float*)d_in[0];
    const int* ei = (const int*)d_in[1];
    const int* batch = (const int*)d_in[2];
    const int N = in_sizes[0] / 64;
    const int E = in_sizes[1] / 2;
    const int* src = ei;
    const int* dst = ei + E;

    const float* w_rel1 = (const float*)d_in[3];
    const float* w_root1 = (const float*)d_in[4];
    const float* b1 = (const float*)d_in[5];
    const float* g1 = (const float*)d_in[6];
    const float* be1 = (const float*)d_in[7];
    const float* w_rel2 = (const float*)d_in[8];
    const float* w_root2 = (const float*)d_in[9];
    const float* b2 = (const float*)d_in[10];
    const float* g2 = (const float*)d_in[11];
    const float* be2 = (const float*)d_in[12];
    const float* w_rel3 = (const float*)d_in[13];
    const float* w_root3 = (const float*)d_in[14];
    const float* b3 = (const float*)d_in[15];
    const float* g3 = (const float*)d_in[16];
    const float* be3 = (const float*)d_in[17];
    const float* w_rel4 = (const float*)d_in[18];
    const float* w_root4 = (const float*)d_in[19];
    const float* b4 = (const float*)d_in[20];
    const float* g4 = (const float*)d_in[21];
    const float* be4 = (const float*)d_in[22];
    const float* w_lin1 = (const float*)d_in[23];
    const float* b_lin1 = (const float*)d_in[24];
    const float* w_lin2 = (const float*)d_in[25];
    const float* b_lin2 = (const float*)d_in[26];

    char* ws = (char*)d_ws;
    size_t off = 0;
    auto alloc = [&](size_t bytes) { size_t o = off; off += (bytes + 255) & ~(size_t)255; return o; };
    int* hmat = (int*)(ws + alloc((size_t)NSORT * NBUCK * 4));
    int* bstart = (int*)(ws + alloc((size_t)(NBUCK + 1) * 4));
    unsigned* ebuf = (unsigned*)(ws + alloc((size_t)E * 4));
    int* csr = (int*)(ws + alloc((size_t)E * 4));
    int* row_start = (int*)(ws + alloc((size_t)(N + 1) * 4));
    float* agg = (float*)(ws + alloc((size_t)N * 32 * 4));
    unsigned short* y1b = (unsigned short*)(ws + alloc((size_t)N * 16 * 2));
    unsigned short* hb = (unsigned short*)(ws + alloc((size_t)N * 64 * 2));
    float* bufA = (float*)(ws + alloc((size_t)N * 64 * 4));
    // zero region: gs (4 layers x 128) + pooled + cntg, contiguous
    float* gs = (float*)(ws + alloc((size_t)(512 + NGRAPHS * 64 + NGRAPHS) * 4));
    float* pooled = gs + 512;
    float* cntg = pooled + NGRAPHS * 64;
    const int zwords = 512 + NGRAPHS * 64 + NGRAPHS;

    const float invN = 1.0f / (float)N;
    const int gbl = (N + 3) / 4;  // gather: 4 waves/block, 1 wave/node

    // ---- CSR build; dispatch 1 also zeroes gs/pooled and runs L1 rel matmul in disjoint blocks ----
    k_bhist<<<1024, 256, 0, stream>>>(dst, hmat, E, x, w_rel1, y1b, gs, zwords, N);
    k_scan<<<1, 512, 0, stream>>>(hmat, bstart);
    k_bscatter<<<NSORT, 256, 0, stream>>>(src, dst, hmat, bstart, ebuf, E);
    k_sort2<<<NBUCK, 256, 0, stream>>>(ebuf, bstart, csr, row_start, N);

    // ---- Layer 1 (64 -> 16) ----
    k_gather<16><<<gbl, 256, 0, stream>>>(y1b, row_start, csr, agg, N);
    k_lin_stats<64, 16, false, true, false><<<LSTAT, 256, 0, stream>>>(
        x, agg, nullptr, w_root1, b1, bufA, gs + 0, N);
    k_bn_elu<16><<<(N * 4 + 255) / 256, 256, 0, stream>>>(bufA, gs + 0, g1, be1, hb, invN, N);

    // ---- Layer 2 (16 -> 32) ----
    k_gather<16><<<gbl, 256, 0, stream>>>(hb, row_start, csr, agg, N);
    k_lin_stats<16, 32, true, false, true><<<LSTAT, 256, 0, stream>>>(
        hb, agg, w_rel2, w_root2, b2, bufA, gs + 128, N);
    k_bn_elu<32><<<(N * 8 + 255) / 256, 256, 0, stream>>>(bufA, gs + 128, g2, be2, hb, invN, N);

    // ---- Layer 3 (32 -> 32) ----
    k_gather<32><<<gbl, 256, 0, stream>>>(hb, row_start, csr, agg, N);
    k_lin_stats<32, 32, true, false, true><<<LSTAT, 256, 0, stream>>>(
        hb, agg, w_rel3, w_root3, b3, bufA, gs + 256, N);
    k_bn_elu<32><<<(N * 8 + 255) / 256, 256, 0, stream>>>(bufA, gs + 256, g3, be3, hb, invN, N);

    // ---- Layer 4 (32 -> 64): lin+stats, then fused BN+ELU+pool ----
    k_gather<32><<<gbl, 256, 0, stream>>>(hb, row_start, csr, agg, N);
    k_lin_stats<32, 64, true, false, true><<<LSTAT, 256, 0, stream>>>(
        hb, agg, w_rel4, w_root4, b4, bufA, gs + 384, N);
    int waves16 = (N + 15) / 16;
    k_bn_elu_pool<<<(waves16 + 3) / 4, 256, 0, stream>>>(
        bufA, gs + 384, g4, be4, batch, pooled, cntg, invN, N);

    // ---- head ----
    k_head<<<1, 256, 0, stream>>>(pooled, cntg, w_lin1, b_lin1, w_lin2, b_lin2, (float*)d_out);
}